// Round 6
// baseline (136.181 us; speedup 1.0000x reference)
//
#include <hip/hip_runtime.h>
#include <stdint.h>

#define HIDDEN 768
#define META 25
#define EDC 300
#define BB 2
#define NMENT 2000
#define NPAIRS 40000
#define M_ROWS (BB * NMENT)       // 4000
#define M_PAD 4096                // 32 * 128
#define N_OUT 1536
#define TOTAL_PAIRS (BB * NPAIRS) // 80000
#define BK 32
#define NBUCK 128                 // 2 batches x 8 i0-groups x 8 i1-groups
#define XCD_BLOCKS 688            // capacity 688*16 = 11008 pairs/XCD (mean 10000, +10 sigma)

typedef __bf16 bf16x8 __attribute__((ext_vector_type(8)));
typedef float f32x4 __attribute__((ext_vector_type(4)));

static __device__ __forceinline__ float bf2f(unsigned short u) {
    union { unsigned int u; float f; } v; v.u = ((unsigned int)u) << 16; return v.f;
}
static __device__ __forceinline__ float2 bf2x(unsigned int u) {
    union { unsigned int x; float f; } lo, hi;
    lo.x = u << 16; hi.x = u & 0xffff0000u;
    float2 r; r.x = lo.f; r.y = hi.f; return r;
}
static __device__ __forceinline__ unsigned short f2bf(float f) {
    union { float f; unsigned int u; } v; v.f = f;
    unsigned int u = v.u;
    unsigned int r = (u + 0x7FFFu + ((u >> 16) & 1u)) >> 16;   // RNE
    return (unsigned short)r;
}

#define GLOAD_LDS16(g, l)                                                            \
    __builtin_amdgcn_global_load_lds((const __attribute__((address_space(1))) void*)(g), \
                                     (__attribute__((address_space(3))) void*)(l), 16, 0, 0)

// ---- fused prep: convM | convW | ed prep | W2->bf16 | zero hist ----
#define NB_CONVM 3072              // (4096*768/4)/256
#define NB_CONVW 576               // 24*24
#define NB_PREP  900               // 300*768/256
#define NB_W2    3                 // 768/256
#define NB_ZERO  1

__global__ __launch_bounds__(256) void k_prep_all(
        const float* __restrict__ M, unsigned short* __restrict__ Mb,
        const float* __restrict__ W1, unsigned short* __restrict__ Wt,
        const float* __restrict__ ed_table, const float* __restrict__ b1,
        unsigned short* __restrict__ Epp,
        const float* __restrict__ W2, unsigned short* __restrict__ W2b,
        int* __restrict__ hist) {
    const int blk = blockIdx.x;
    const int t = threadIdx.x;
    if (blk < NB_CONVM) {
        int idx = (blk * 256 + t) * 4;
        int row = idx / HIDDEN;
        ushort4 o;
        if (row < M_ROWS) {
            const float4 v = *(const float4*)(M + idx);
            o.x = f2bf(v.x); o.y = f2bf(v.y); o.z = f2bf(v.z); o.w = f2bf(v.w);
        } else {
            o.x = 0; o.y = 0; o.z = 0; o.w = 0;
        }
        *(ushort4*)(Mb + idx) = o;
    } else if (blk < NB_CONVM + NB_CONVW) {
        __shared__ float tile[32][68];
        int id = blk - NB_CONVM;
        int nt = id % 24, kt = id / 24;
        int n0 = nt * 64, k0 = kt * 32;
        int tk = t >> 4, tn = (t & 15) * 4;
        int srcRowOff = (n0 < HIDDEN) ? 0 : HIDDEN;
        int srcColBase = (n0 < HIDDEN) ? n0 : (n0 - HIDDEN);
        {
            const float4 v0 = *(const float4*)(W1 + (size_t)(k0 + tk + srcRowOff) * HIDDEN + srcColBase + tn);
            tile[tk][tn] = v0.x; tile[tk][tn + 1] = v0.y; tile[tk][tn + 2] = v0.z; tile[tk][tn + 3] = v0.w;
            const float4 v1 = *(const float4*)(W1 + (size_t)(k0 + tk + 16 + srcRowOff) * HIDDEN + srcColBase + tn);
            tile[tk + 16][tn] = v1.x; tile[tk + 16][tn + 1] = v1.y; tile[tk + 16][tn + 2] = v1.z; tile[tk + 16][tn + 3] = v1.w;
        }
        __syncthreads();
        int wn = t >> 2, wk = (t & 3) * 8;
        unsigned int p0 = (unsigned int)f2bf(tile[wk + 0][wn]) | ((unsigned int)f2bf(tile[wk + 1][wn]) << 16);
        unsigned int p1 = (unsigned int)f2bf(tile[wk + 2][wn]) | ((unsigned int)f2bf(tile[wk + 3][wn]) << 16);
        unsigned int p2 = (unsigned int)f2bf(tile[wk + 4][wn]) | ((unsigned int)f2bf(tile[wk + 5][wn]) << 16);
        unsigned int p3 = (unsigned int)f2bf(tile[wk + 6][wn]) | ((unsigned int)f2bf(tile[wk + 7][wn]) << 16);
        uint4 pk; pk.x = p0; pk.y = p1; pk.z = p2; pk.w = p3;
        *(uint4*)(Wt + (size_t)(n0 + wn) * HIDDEN + k0 + wk) = pk;
    } else if (blk < NB_CONVM + NB_CONVW + NB_PREP) {
        int id = (blk - NB_CONVM - NB_CONVW) * 256 + t;
        int e = id / HIDDEN, n = id - e * HIDDEN;
        float acc = b1[n];
#pragma unroll
        for (int k = 0; k < META; k++)
            acc += ed_table[e * META + k] * W1[(size_t)(2 * HIDDEN + k) * HIDDEN + n];
        Epp[id] = f2bf(acc);
    } else if (blk < NB_CONVM + NB_CONVW + NB_PREP + NB_W2) {
        int id = (blk - NB_CONVM - NB_CONVW - NB_PREP) * 256 + t;
        if (id < HIDDEN) W2b[id] = f2bf(W2[id]);
    } else {
        if (t < NBUCK) hist[t] = 0;   // ws is poisoned 0xAA every call -> must zero
    }
}

static __device__ __forceinline__ int bucket_of(int p, int i0, int i1) {
    int b = (p >= NPAIRS) ? 1 : 0;
    return b * 64 + (i0 / 250) * 8 + (i1 / 250);
}

// ---- hist: per-block LDS hist -> global atomics ----
__global__ __launch_bounds__(256) void k_hist(const int* __restrict__ pairs,
                                              int* __restrict__ hist) {
    __shared__ int h[NBUCK];
    int t = threadIdx.x;
    if (t < NBUCK) h[t] = 0;
    __syncthreads();
    int p = blockIdx.x * 256 + t;
    if (p < TOTAL_PAIRS) {
        int2 pr = *(const int2*)(pairs + (size_t)p * 2);
        atomicAdd(&h[bucket_of(p, pr.x, pr.y)], 1);
    }
    __syncthreads();
    if (t < NBUCK && h[t]) atomicAdd(&hist[t], h[t]);
}

// ---- scan: exclusive prefix + cursor init (serial, 128 elems) ----
__global__ void k_scan(const int* __restrict__ hist, int* __restrict__ off,
                       int* __restrict__ cursor) {
    if (threadIdx.x == 0 && blockIdx.x == 0) {
        int s = 0;
        for (int i = 0; i < NBUCK; i++) { off[i] = s; cursor[i] = s; s += hist[i]; }
        off[NBUCK] = s;
    }
}

// ---- scatter: block-aggregated counting-sort scatter ----
__global__ __launch_bounds__(256) void k_scatter(const int* __restrict__ pairs,
                                                 int* __restrict__ cursor,
                                                 int* __restrict__ perm) {
    __shared__ int h[NBUCK], base[NBUCK];
    int t = threadIdx.x;
    if (t < NBUCK) h[t] = 0;
    __syncthreads();
    int p = blockIdx.x * 256 + t;
    int bk = 0, lr = 0;
    bool valid = p < TOTAL_PAIRS;
    if (valid) {
        int2 pr = *(const int2*)(pairs + (size_t)p * 2);
        bk = bucket_of(p, pr.x, pr.y);
        lr = atomicAdd(&h[bk], 1);
    }
    __syncthreads();
    if (t < NBUCK && h[t]) base[t] = atomicAdd(&cursor[t], h[t]);
    __syncthreads();
    if (valid) perm[base[bk] + lr] = p;
}

// ---- AW[4096][1536] = Mb @ Wt^T ----
__global__ __launch_bounds__(256) void k_gemm(const unsigned short* __restrict__ Mb,
                                              const unsigned short* __restrict__ Wt,
                                              unsigned short* __restrict__ AW) {
    __shared__ unsigned short As[128 * BK];
    __shared__ unsigned short Bs[64 * BK];
    const int m0 = blockIdx.x * 128;
    const int n0 = blockIdx.y * 64;
    const int t = threadIdx.x, w = t >> 6, lane = t & 63;
    const int wm = (w & 1) * 64, wn = (w >> 1) * 32;
    const int q = lane >> 4, r = lane & 15;
    const int lrow = lane >> 2, lcol = (lane & 3) * 8;
    const unsigned short* gA = Mb + (size_t)(m0 + w * 32 + lrow) * HIDDEN + lcol;
    const unsigned short* gB = Wt + (size_t)(n0 + w * 16 + lrow) * HIDDEN + lcol;
    unsigned short* lA = As + (w * 32) * BK;
    unsigned short* lB = Bs + (w * 16) * BK;
    f32x4 acc[4][2] = {};
    for (int k0 = 0; k0 < HIDDEN; k0 += BK) {
        GLOAD_LDS16(gA + k0, lA);
        GLOAD_LDS16(gA + k0 + 16 * HIDDEN, lA + 16 * BK);
        GLOAD_LDS16(gB + k0, lB);
        __syncthreads();
        bf16x8 af[4], bfr[2];
#pragma unroll
        for (int i = 0; i < 4; i++) af[i]  = *(const bf16x8*)&As[(wm + i * 16 + r) * BK + q * 8];
#pragma unroll
        for (int j = 0; j < 2; j++) bfr[j] = *(const bf16x8*)&Bs[(wn + j * 16 + r) * BK + q * 8];
#pragma unroll
        for (int i = 0; i < 4; i++)
#pragma unroll
            for (int j = 0; j < 2; j++)
                acc[i][j] = __builtin_amdgcn_mfma_f32_16x16x32_bf16(af[i], bfr[j], acc[i][j], 0, 0, 0);
        __syncthreads();
    }
    const int colb = n0 + wn + (lane & 15);
    const int rowb = m0 + wm + (lane >> 4) * 4;
#pragma unroll
    for (int i = 0; i < 4; i++)
#pragma unroll
        for (int j = 0; j < 2; j++) {
            unsigned short* dst = AW + (size_t)(rowb + i * 16) * N_OUT + colb + j * 16;
#pragma unroll
            for (int reg = 0; reg < 4; reg++)
                dst[(size_t)reg * N_OUT] = f2bf(acc[i][j][reg]);
        }
}

// ---- pair phase: bucket-sorted, XCD-pinned (blockIdx%8 round-robin heuristic) ----
// XCD x handles buckets with i0-group == x: perm runs [off[x*8],off[x*8+8]) (batch 0)
// and [off[64+x*8],off[64+x*8+8]) (batch 1). 4 pairs/wave, same math as before.
__global__ __launch_bounds__(256) void k_pair(const unsigned short* __restrict__ AW,
                                              const unsigned short* __restrict__ Epp,
                                              const unsigned short* __restrict__ W2b,
                                              const float* __restrict__ b2,
                                              const int* __restrict__ pairs,
                                              const int* __restrict__ eds,
                                              const int* __restrict__ off,
                                              const int* __restrict__ perm,
                                              float* __restrict__ out) {
    const int xcd = blockIdx.x & 7;
    const int kb  = blockIdx.x >> 3;
    const int lane = threadIdx.x & 63;
    const int wv   = threadIdx.x >> 6;
    const int s1 = off[xcd * 8],      e1 = off[xcd * 8 + 8];
    const int s2 = off[64 + xcd * 8], e2 = off[64 + xcd * 8 + 8];
    const int len1 = e1 - s1;
    const int len  = len1 + (e2 - s2);
    const int l0 = kb * 16 + wv * 4;
    if (l0 >= len) return;   // no barriers below: per-wave early exit is safe

    int   pidx[4];
    bool  val[4];
#pragma unroll
    for (int i = 0; i < 4; i++) {
        int l = l0 + i;
        val[i] = l < len;
        int pos = (l < len1) ? (s1 + l) : (s2 + (l - len1));
        if (!val[i]) pos = s1;                 // safe fallback (l0<len => s1 valid range start)
        if (pos >= TOTAL_PAIRS) pos = 0;       // paranoia clamp
        pidx[i] = perm[pos];
    }

    const int n0 = lane * 8;
    const int n1 = 512 + lane * 4;

    const unsigned short* a1p[4];
    const unsigned short* a2p[4];
    const unsigned short* epp[4];
#pragma unroll
    for (int i = 0; i < 4; i++) {
        int p = pidx[i];
        int2 pr = *(const int2*)(pairs + (size_t)p * 2);
        int ed = eds[p];
        size_t base = (p >= NPAIRS) ? (size_t)NMENT : 0;
        a1p[i] = AW + (base + pr.x) * N_OUT;
        a2p[i] = AW + (base + pr.y) * N_OUT + HIDDEN;
        epp[i] = Epp + (size_t)ed * HIDDEN;
    }

    uint4   w0 = *(const uint4*)(W2b + n0);
    ushort4 w1 = *(const ushort4*)(W2b + n1);
    uint4   x10 = *(const uint4*)(a1p[0] + n0), x20 = *(const uint4*)(a2p[0] + n0), xe0 = *(const uint4*)(epp[0] + n0);
    uint4   y10 = *(const uint4*)(a1p[1] + n0), y20 = *(const uint4*)(a2p[1] + n0), ye0 = *(const uint4*)(epp[1] + n0);
    uint4   z10 = *(const uint4*)(a1p[2] + n0), z20 = *(const uint4*)(a2p[2] + n0), ze0 = *(const uint4*)(epp[2] + n0);
    uint4   v10 = *(const uint4*)(a1p[3] + n0), v20 = *(const uint4*)(a2p[3] + n0), ve0 = *(const uint4*)(epp[3] + n0);
    ushort4 x11 = *(const ushort4*)(a1p[0] + n1), x21 = *(const ushort4*)(a2p[0] + n1), xe1 = *(const ushort4*)(epp[0] + n1);
    ushort4 y11 = *(const ushort4*)(a1p[1] + n1), y21 = *(const ushort4*)(a2p[1] + n1), ye1 = *(const ushort4*)(epp[1] + n1);
    ushort4 z11 = *(const ushort4*)(a1p[2] + n1), z21 = *(const ushort4*)(a2p[2] + n1), ze1 = *(const ushort4*)(epp[2] + n1);
    ushort4 v11 = *(const ushort4*)(a1p[3] + n1), v21 = *(const ushort4*)(a2p[3] + n1), ve1 = *(const ushort4*)(epp[3] + n1);

    float acc0 = 0.f, acc1 = 0.f, acc2 = 0.f, acc3 = 0.f;
#define ACC2(acc, ua, ub, ue, uw)                                              \
    {                                                                          \
        float2 fa = bf2x(ua), fb = bf2x(ub), fe = bf2x(ue), fw = bf2x(uw);     \
        float h0 = fmaxf(fa.x + fb.x + fe.x, 0.f);                             \
        float h1 = fmaxf(fa.y + fb.y + fe.y, 0.f);                             \
        acc += h0 * fw.x + h1 * fw.y;                                          \
    }
#define ACC1(acc, sa, sb, se, sw)                                              \
    {                                                                          \
        float h = fmaxf(bf2f(sa) + bf2f(sb) + bf2f(se), 0.f);                  \
        acc += h * bf2f(sw);                                                   \
    }
    ACC2(acc0, x10.x, x20.x, xe0.x, w0.x); ACC2(acc0, x10.y, x20.y, xe0.y, w0.y);
    ACC2(acc0, x10.z, x20.z, xe0.z, w0.z); ACC2(acc0, x10.w, x20.w, xe0.w, w0.w);
    ACC1(acc0, x11.x, x21.x, xe1.x, w1.x); ACC1(acc0, x11.y, x21.y, xe1.y, w1.y);
    ACC1(acc0, x11.z, x21.z, xe1.z, w1.z); ACC1(acc0, x11.w, x21.w, xe1.w, w1.w);
    ACC2(acc1, y10.x, y20.x, ye0.x, w0.x); ACC2(acc1, y10.y, y20.y, ye0.y, w0.y);
    ACC2(acc1, y10.z, y20.z, ye0.z, w0.z); ACC2(acc1, y10.w, y20.w, ye0.w, w0.w);
    ACC1(acc1, y11.x, y21.x, ye1.x, w1.x); ACC1(acc1, y11.y, y21.y, ye1.y, w1.y);
    ACC1(acc1, y11.z, y21.z, ye1.z, w1.z); ACC1(acc1, y11.w, y21.w, ye1.w, w1.w);
    ACC2(acc2, z10.x, z20.x, ze0.x, w0.x); ACC2(acc2, z10.y, z20.y, ze0.y, w0.y);
    ACC2(acc2, z10.z, z20.z, ze0.z, w0.z); ACC2(acc2, z10.w, z20.w, ze0.w, w0.w);
    ACC1(acc2, z11.x, z21.x, ze1.x, w1.x); ACC1(acc2, z11.y, z21.y, ze1.y, w1.y);
    ACC1(acc2, z11.z, z21.z, ze1.z, w1.z); ACC1(acc2, z11.w, z21.w, ze1.w, w1.w);
    ACC2(acc3, v10.x, v20.x, ve0.x, w0.x); ACC2(acc3, v10.y, v20.y, ve0.y, w0.y);
    ACC2(acc3, v10.z, v20.z, ve0.z, w0.z); ACC2(acc3, v10.w, v20.w, ve0.w, w0.w);
    ACC1(acc3, v11.x, v21.x, ve1.x, w1.x); ACC1(acc3, v11.y, v21.y, ve1.y, w1.y);
    ACC1(acc3, v11.z, v21.z, ve1.z, w1.z); ACC1(acc3, v11.w, v21.w, ve1.w, w1.w);
#undef ACC2
#undef ACC1
#pragma unroll
    for (int o = 32; o > 0; o >>= 1) {
        acc0 += __shfl_xor(acc0, o, 64);
        acc1 += __shfl_xor(acc1, o, 64);
        acc2 += __shfl_xor(acc2, o, 64);
        acc3 += __shfl_xor(acc3, o, 64);
    }
    if (lane == 0) {
        float bias = b2[0];
        if (val[0]) out[pidx[0]] = acc0 + bias;
        if (val[1]) out[pidx[1]] = acc1 + bias;
        if (val[2]) out[pidx[2]] = acc2 + bias;
        if (val[3]) out[pidx[3]] = acc3 + bias;
    }
}

extern "C" void kernel_launch(void* const* d_in, const int* in_sizes, int n_in,
                              void* d_out, int out_size, void* d_ws, size_t ws_size,
                              hipStream_t stream) {
    const float* mention  = (const float*)d_in[0];
    const int*   pairs    = (const int*)d_in[1];
    const int*   eds      = (const int*)d_in[2];
    const float* ed_table = (const float*)d_in[3];
    const float* W1       = (const float*)d_in[4];
    const float* b1       = (const float*)d_in[5];
    const float* W2       = (const float*)d_in[6];
    const float* b2       = (const float*)d_in[7];
    float* out = (float*)d_out;

    char* ws = (char*)d_ws;
    unsigned short* Mb     = (unsigned short*)(ws);                 // @0        6,291,456
    unsigned short* Wt     = (unsigned short*)(ws + 6291456);       // @6.29M    2,359,296
    unsigned short* AW     = (unsigned short*)(ws + 8650752);       // @8.65M   12,582,912
    unsigned short* Epp    = (unsigned short*)(ws + 21233664);      // @21.2M      460,800
    unsigned short* W2b    = (unsigned short*)(ws + 21694464);      // @21.69M       1,536
    int*            hist   = (int*)(ws + 21696000);                 //                 512
    int*            cursor = (int*)(ws + 21696512);                 //                 512
    int*            offb   = (int*)(ws + 21697024);                 //           129*4=516 (pad 1024)
    int*            perm   = (int*)(ws + 21698048);                 //             320,000

    k_prep_all<<<dim3(NB_CONVM + NB_CONVW + NB_PREP + NB_W2 + NB_ZERO), dim3(256), 0, stream>>>(
        mention, Mb, W1, Wt, ed_table, b1, Epp, W2, W2b, hist);
    k_hist<<<dim3((TOTAL_PAIRS + 255) / 256), dim3(256), 0, stream>>>(pairs, hist);
    k_scan<<<dim3(1), dim3(64), 0, stream>>>(hist, offb, cursor);
    k_scatter<<<dim3((TOTAL_PAIRS + 255) / 256), dim3(256), 0, stream>>>(pairs, cursor, perm);
    k_gemm<<<dim3(M_PAD / 128, N_OUT / 64), dim3(256), 0, stream>>>(Mb, Wt, AW);
    k_pair<<<dim3(8 * XCD_BLOCKS), dim3(256), 0, stream>>>(AW, Epp, W2b, b2, pairs, eds, offb, perm, out);
}

// Round 7
// 116.430 us; speedup vs baseline: 1.1696x; 1.1696x over previous
//
#include <hip/hip_runtime.h>
#include <stdint.h>

#define HIDDEN 768
#define META 25
#define EDC 300
#define BB 2
#define NMENT 2000
#define NPAIRS 40000
#define M_ROWS (BB * NMENT)       // 4000
#define M_PAD 4096                // 32 * 128
#define N_OUT 1536
#define TOTAL_PAIRS (BB * NPAIRS) // 80000
#define BK 64                     // row = 128 B = full 32-bank span (enables swizzle)

typedef __bf16 bf16x8 __attribute__((ext_vector_type(8)));
typedef float f32x4 __attribute__((ext_vector_type(4)));

static __device__ __forceinline__ float bf2f(unsigned short u) {
    union { unsigned int u; float f; } v; v.u = ((unsigned int)u) << 16; return v.f;
}
static __device__ __forceinline__ float2 bf2x(unsigned int u) {
    union { unsigned int x; float f; } lo, hi;
    lo.x = u << 16; hi.x = u & 0xffff0000u;
    float2 r; r.x = lo.f; r.y = hi.f; return r;
}
static __device__ __forceinline__ unsigned short f2bf(float f) {
    union { float f; unsigned int u; } v; v.f = f;
    unsigned int u = v.u;
    unsigned int r = (u + 0x7FFFu + ((u >> 16) & 1u)) >> 16;   // RNE
    return (unsigned short)r;
}

#define GLOAD_LDS16(g, l)                                                            \
    __builtin_amdgcn_global_load_lds((const __attribute__((address_space(1))) void*)(g), \
                                     (__attribute__((address_space(3))) void*)(l), 16, 0, 0)

// ---- fused prep: convM | convW | ed prep | W2->bf16 ----
#define NB_CONVM 3072              // (4096*768/4)/256
#define NB_CONVW 576               // 24*24
#define NB_PREP  900               // 300*768/256
#define NB_W2    3                 // 768/256

__global__ __launch_bounds__(256) void k_prep_all(
        const float* __restrict__ M, unsigned short* __restrict__ Mb,
        const float* __restrict__ W1, unsigned short* __restrict__ Wt,
        const float* __restrict__ ed_table, const float* __restrict__ b1,
        unsigned short* __restrict__ Epp,
        const float* __restrict__ W2, unsigned short* __restrict__ W2b) {
    const int blk = blockIdx.x;
    const int t = threadIdx.x;
    if (blk < NB_CONVM) {
        int idx = (blk * 256 + t) * 4;
        int row = idx / HIDDEN;
        ushort4 o;
        if (row < M_ROWS) {
            const float4 v = *(const float4*)(M + idx);
            o.x = f2bf(v.x); o.y = f2bf(v.y); o.z = f2bf(v.z); o.w = f2bf(v.w);
        } else {
            o.x = 0; o.y = 0; o.z = 0; o.w = 0;
        }
        *(ushort4*)(Mb + idx) = o;
    } else if (blk < NB_CONVM + NB_CONVW) {
        __shared__ float tile[32][68];
        int id = blk - NB_CONVM;
        int nt = id % 24, kt = id / 24;
        int n0 = nt * 64, k0 = kt * 32;
        int tk = t >> 4, tn = (t & 15) * 4;
        int srcRowOff = (n0 < HIDDEN) ? 0 : HIDDEN;
        int srcColBase = (n0 < HIDDEN) ? n0 : (n0 - HIDDEN);
        {
            const float4 v0 = *(const float4*)(W1 + (size_t)(k0 + tk + srcRowOff) * HIDDEN + srcColBase + tn);
            tile[tk][tn] = v0.x; tile[tk][tn + 1] = v0.y; tile[tk][tn + 2] = v0.z; tile[tk][tn + 3] = v0.w;
            const float4 v1 = *(const float4*)(W1 + (size_t)(k0 + tk + 16 + srcRowOff) * HIDDEN + srcColBase + tn);
            tile[tk + 16][tn] = v1.x; tile[tk + 16][tn + 1] = v1.y; tile[tk + 16][tn + 2] = v1.z; tile[tk + 16][tn + 3] = v1.w;
        }
        __syncthreads();
        int wn = t >> 2, wk = (t & 3) * 8;
        unsigned int p0 = (unsigned int)f2bf(tile[wk + 0][wn]) | ((unsigned int)f2bf(tile[wk + 1][wn]) << 16);
        unsigned int p1 = (unsigned int)f2bf(tile[wk + 2][wn]) | ((unsigned int)f2bf(tile[wk + 3][wn]) << 16);
        unsigned int p2 = (unsigned int)f2bf(tile[wk + 4][wn]) | ((unsigned int)f2bf(tile[wk + 5][wn]) << 16);
        unsigned int p3 = (unsigned int)f2bf(tile[wk + 6][wn]) | ((unsigned int)f2bf(tile[wk + 7][wn]) << 16);
        uint4 pk; pk.x = p0; pk.y = p1; pk.z = p2; pk.w = p3;
        *(uint4*)(Wt + (size_t)(n0 + wn) * HIDDEN + k0 + wk) = pk;
    } else if (blk < NB_CONVM + NB_CONVW + NB_PREP) {
        int id = (blk - NB_CONVM - NB_CONVW) * 256 + t;
        int e = id / HIDDEN, n = id - e * HIDDEN;
        float acc = b1[n];
#pragma unroll
        for (int k = 0; k < META; k++)
            acc += ed_table[e * META + k] * W1[(size_t)(2 * HIDDEN + k) * HIDDEN + n];
        Epp[id] = f2bf(acc);
    } else {
        int id = (blk - NB_CONVM - NB_CONVW - NB_PREP) * 256 + t;
        if (id < HIDDEN) W2b[id] = f2bf(W2[id]);
    }
}

// ---- AW[4096][1536] = Mb @ Wt^T ----
// 128x64 block tile, BK=64, grid 32x24 = 768 blocks = 3/CU.
// LDS layout: [m][k] rows of 64 shorts (128 B = 32 banks), k-line of row m
// rotated by (m%8)*8 shorts via the GLOBAL-side address (global_load_lds's
// LDS side is fixed lane*16B). Frag ds_read_b128 then spreads the 16 lanes
// of a quad across all 8 bank-groups -> 2-way (free) instead of 8-way.
__global__ __launch_bounds__(256) void k_gemm(const unsigned short* __restrict__ Mb,
                                              const unsigned short* __restrict__ Wt,
                                              unsigned short* __restrict__ AW) {
    __shared__ unsigned short As[128 * BK];   // 16 KB
    __shared__ unsigned short Bs[64 * BK];    // 8 KB
    const int m0 = blockIdx.x * 128;
    const int n0 = blockIdx.y * 64;
    const int t = threadIdx.x, w = t >> 6, lane = t & 63;
    const int wm = (w & 1) * 64, wn = (w >> 1) * 32;
    const int q = lane >> 4, r = lane & 15;
    // staging: one instr covers 8 rows x 128 B; lane j -> row j>>3, swizzled col
    const int lrow = lane >> 3;
    const int lcol = ((((lane & 7) - lrow) & 7)) * 8;      // shorts
    const unsigned short* gA = Mb + (size_t)(m0 + w * 32 + lrow) * HIDDEN + lcol;
    const unsigned short* gB = Wt + (size_t)(n0 + w * 16 + lrow) * HIDDEN + lcol;
    unsigned short* lA = As + (w * 32) * BK;               // wave-uniform LDS base
    unsigned short* lB = Bs + (w * 16) * BK;
    f32x4 acc[4][2] = {};
    for (int k0 = 0; k0 < HIDDEN; k0 += BK) {
        GLOAD_LDS16(gA + k0, lA);
        GLOAD_LDS16(gA + k0 + 8 * HIDDEN,  lA + 8 * BK);
        GLOAD_LDS16(gA + k0 + 16 * HIDDEN, lA + 16 * BK);
        GLOAD_LDS16(gA + k0 + 24 * HIDDEN, lA + 24 * BK);
        GLOAD_LDS16(gB + k0, lB);
        GLOAD_LDS16(gB + k0 + 8 * HIDDEN,  lB + 8 * BK);
        __syncthreads();
        bf16x8 af[4][2], bfr[2][2];
        const int rs = r & 7;
#pragma unroll
        for (int i = 0; i < 4; i++)
#pragma unroll
            for (int s = 0; s < 2; s++)
                af[i][s] = *(const bf16x8*)&As[(wm + i * 16 + r) * BK + 8 * ((q + 4 * s + rs) & 7)];
#pragma unroll
        for (int j = 0; j < 2; j++)
#pragma unroll
            for (int s = 0; s < 2; s++)
                bfr[j][s] = *(const bf16x8*)&Bs[(wn + j * 16 + r) * BK + 8 * ((q + 4 * s + rs) & 7)];
#pragma unroll
        for (int i = 0; i < 4; i++)
#pragma unroll
            for (int j = 0; j < 2; j++) {
                acc[i][j] = __builtin_amdgcn_mfma_f32_16x16x32_bf16(af[i][0], bfr[j][0], acc[i][j], 0, 0, 0);
                acc[i][j] = __builtin_amdgcn_mfma_f32_16x16x32_bf16(af[i][1], bfr[j][1], acc[i][j], 0, 0, 0);
            }
        __syncthreads();
    }
    // C/D layout: col = lane&15, row = (lane>>4)*4 + reg
    const int colb = n0 + wn + (lane & 15);
    const int rowb = m0 + wm + (lane >> 4) * 4;
#pragma unroll
    for (int i = 0; i < 4; i++)
#pragma unroll
        for (int j = 0; j < 2; j++) {
            unsigned short* dst = AW + (size_t)(rowb + i * 16) * N_OUT + colb + j * 16;
#pragma unroll
            for (int reg = 0; reg < 4; reg++)
                dst[(size_t)reg * N_OUT] = f2bf(acc[i][j][reg]);
        }
}

// ---- pair phase: 4 pairs per wave (R5 version, known-good) ----
__global__ __launch_bounds__(256) void k_pair(const unsigned short* __restrict__ AW,
                                              const unsigned short* __restrict__ Epp,
                                              const unsigned short* __restrict__ W2b,
                                              const float* __restrict__ b2,
                                              const int* __restrict__ pairs,
                                              const int* __restrict__ eds,
                                              float* __restrict__ out) {
    const int wid = blockIdx.x * 4 + (threadIdx.x >> 6);   // 0..19999
    const int lane = threadIdx.x & 63;
    const int p0 = wid * 4;
    const int b = (p0 >= NPAIRS) ? 1 : 0;                   // 40000 % 4 == 0: group shares batch
    const int n0 = lane * 8;
    const int n1 = 512 + lane * 4;

    const int4 pr01 = *(const int4*)(pairs + (size_t)p0 * 2);
    const int4 pr23 = *(const int4*)(pairs + (size_t)p0 * 2 + 4);
    const int4 ed4  = *(const int4*)(eds + p0);

    const size_t base = (size_t)(b * NMENT);
    const unsigned short* a1p0 = AW + (base + pr01.x) * N_OUT;
    const unsigned short* a2p0 = AW + (base + pr01.y) * N_OUT + HIDDEN;
    const unsigned short* ep0  = Epp + (size_t)ed4.x * HIDDEN;
    const unsigned short* a1p1 = AW + (base + pr01.z) * N_OUT;
    const unsigned short* a2p1 = AW + (base + pr01.w) * N_OUT + HIDDEN;
    const unsigned short* ep1  = Epp + (size_t)ed4.y * HIDDEN;
    const unsigned short* a1p2 = AW + (base + pr23.x) * N_OUT;
    const unsigned short* a2p2 = AW + (base + pr23.y) * N_OUT + HIDDEN;
    const unsigned short* ep2  = Epp + (size_t)ed4.z * HIDDEN;
    const unsigned short* a1p3 = AW + (base + pr23.z) * N_OUT;
    const unsigned short* a2p3 = AW + (base + pr23.w) * N_OUT + HIDDEN;
    const unsigned short* ep3  = Epp + (size_t)ed4.w * HIDDEN;

    uint4   w0 = *(const uint4*)(W2b + n0);
    ushort4 w1 = *(const ushort4*)(W2b + n1);
    uint4   x10 = *(const uint4*)(a1p0 + n0), x20 = *(const uint4*)(a2p0 + n0), xe0 = *(const uint4*)(ep0 + n0);
    uint4   y10 = *(const uint4*)(a1p1 + n0), y20 = *(const uint4*)(a2p1 + n0), ye0 = *(const uint4*)(ep1 + n0);
    uint4   z10 = *(const uint4*)(a1p2 + n0), z20 = *(const uint4*)(a2p2 + n0), ze0 = *(const uint4*)(ep2 + n0);
    uint4   v10 = *(const uint4*)(a1p3 + n0), v20 = *(const uint4*)(a2p3 + n0), ve0 = *(const uint4*)(ep3 + n0);
    ushort4 x11 = *(const ushort4*)(a1p0 + n1), x21 = *(const ushort4*)(a2p0 + n1), xe1 = *(const ushort4*)(ep0 + n1);
    ushort4 y11 = *(const ushort4*)(a1p1 + n1), y21 = *(const ushort4*)(a2p1 + n1), ye1 = *(const ushort4*)(ep1 + n1);
    ushort4 z11 = *(const ushort4*)(a1p2 + n1), z21 = *(const ushort4*)(a2p2 + n1), ze1 = *(const ushort4*)(ep2 + n1);
    ushort4 v11 = *(const ushort4*)(a1p3 + n1), v21 = *(const ushort4*)(a2p3 + n1), ve1 = *(const ushort4*)(ep3 + n1);

    float acc0 = 0.f, acc1 = 0.f, acc2 = 0.f, acc3 = 0.f;
#define ACC2(acc, ua, ub, ue, uw)                                              \
    {                                                                          \
        float2 fa = bf2x(ua), fb = bf2x(ub), fe = bf2x(ue), fw = bf2x(uw);     \
        float h0 = fmaxf(fa.x + fb.x + fe.x, 0.f);                             \
        float h1 = fmaxf(fa.y + fb.y + fe.y, 0.f);                             \
        acc += h0 * fw.x + h1 * fw.y;                                          \
    }
#define ACC1(acc, sa, sb, se, sw)                                              \
    {                                                                          \
        float h = fmaxf(bf2f(sa) + bf2f(sb) + bf2f(se), 0.f);                  \
        acc += h * bf2f(sw);                                                   \
    }
    ACC2(acc0, x10.x, x20.x, xe0.x, w0.x); ACC2(acc0, x10.y, x20.y, xe0.y, w0.y);
    ACC2(acc0, x10.z, x20.z, xe0.z, w0.z); ACC2(acc0, x10.w, x20.w, xe0.w, w0.w);
    ACC1(acc0, x11.x, x21.x, xe1.x, w1.x); ACC1(acc0, x11.y, x21.y, xe1.y, w1.y);
    ACC1(acc0, x11.z, x21.z, xe1.z, w1.z); ACC1(acc0, x11.w, x21.w, xe1.w, w1.w);
    ACC2(acc1, y10.x, y20.x, ye0.x, w0.x); ACC2(acc1, y10.y, y20.y, ye0.y, w0.y);
    ACC2(acc1, y10.z, y20.z, ye0.z, w0.z); ACC2(acc1, y10.w, y20.w, ye0.w, w0.w);
    ACC1(acc1, y11.x, y21.x, ye1.x, w1.x); ACC1(acc1, y11.y, y21.y, ye1.y, w1.y);
    ACC1(acc1, y11.z, y21.z, ye1.z, w1.z); ACC1(acc1, y11.w, y21.w, ye1.w, w1.w);
    ACC2(acc2, z10.x, z20.x, ze0.x, w0.x); ACC2(acc2, z10.y, z20.y, ze0.y, w0.y);
    ACC2(acc2, z10.z, z20.z, ze0.z, w0.z); ACC2(acc2, z10.w, z20.w, ze0.w, w0.w);
    ACC1(acc2, z11.x, z21.x, ze1.x, w1.x); ACC1(acc2, z11.y, z21.y, ze1.y, w1.y);
    ACC1(acc2, z11.z, z21.z, ze1.z, w1.z); ACC1(acc2, z11.w, z21.w, ze1.w, w1.w);
    ACC2(acc3, v10.x, v20.x, ve0.x, w0.x); ACC2(acc3, v10.y, v20.y, ve0.y, w0.y);
    ACC2(acc3, v10.z, v20.z, ve0.z, w0.z); ACC2(acc3, v10.w, v20.w, ve0.w, w0.w);
    ACC1(acc3, v11.x, v21.x, ve1.x, w1.x); ACC1(acc3, v11.y, v21.y, ve1.y, w1.y);
    ACC1(acc3, v11.z, v21.z, ve1.z, w1.z); ACC1(acc3, v11.w, v21.w, ve1.w, w1.w);
#undef ACC2
#undef ACC1
#pragma unroll
    for (int o = 32; o > 0; o >>= 1) {
        acc0 += __shfl_xor(acc0, o, 64);
        acc1 += __shfl_xor(acc1, o, 64);
        acc2 += __shfl_xor(acc2, o, 64);
        acc3 += __shfl_xor(acc3, o, 64);
    }
    if (lane == 0) {
        float bias = b2[0];
        float4 o; o.x = acc0 + bias; o.y = acc1 + bias; o.z = acc2 + bias; o.w = acc3 + bias;
        *(float4*)(out + p0) = o;
    }
}

extern "C" void kernel_launch(void* const* d_in, const int* in_sizes, int n_in,
                              void* d_out, int out_size, void* d_ws, size_t ws_size,
                              hipStream_t stream) {
    const float* mention  = (const float*)d_in[0];
    const int*   pairs    = (const int*)d_in[1];
    const int*   eds      = (const int*)d_in[2];
    const float* ed_table = (const float*)d_in[3];
    const float* W1       = (const float*)d_in[4];
    const float* b1       = (const float*)d_in[5];
    const float* W2       = (const float*)d_in[6];
    const float* b2       = (const float*)d_in[7];
    float* out = (float*)d_out;

    char* ws = (char*)d_ws;
    unsigned short* Mb  = (unsigned short*)(ws);                       // 4096*768*2  = 6,291,456
    unsigned short* Wt  = (unsigned short*)(ws + 6291456);             // 1536*768*2  = 2,359,296
    unsigned short* AW  = (unsigned short*)(ws + 8650752);             // 4096*1536*2 = 12,582,912
    unsigned short* Epp = (unsigned short*)(ws + 21233664);            // 300*768*2   = 460,800
    unsigned short* W2b = (unsigned short*)(ws + 21694464);            // 768*2

    k_prep_all<<<dim3(NB_CONVM + NB_CONVW + NB_PREP + NB_W2), dim3(256), 0, stream>>>(
        mention, Mb, W1, Wt, ed_table, b1, Epp, W2, W2b);
    k_gemm<<<dim3(M_PAD / 128, N_OUT / 64), dim3(256), 0, stream>>>(Mb, Wt, AW);
    k_pair<<<dim3(TOTAL_PAIRS / 16), dim3(256), 0, stream>>>(AW, Epp, W2b, b2, pairs, eds, out);
}

// Round 8
// 115.544 us; speedup vs baseline: 1.1786x; 1.0077x over previous
//
#include <hip/hip_runtime.h>
#include <stdint.h>

#define HIDDEN 768
#define META 25
#define EDC 300
#define BB 2
#define NMENT 2000
#define NPAIRS 40000
#define M_ROWS (BB * NMENT)       // 4000
#define M_PAD 4096                // 32 * 128
#define N_OUT 1536
#define TOTAL_PAIRS (BB * NPAIRS) // 80000
#define BK 64                     // row = 128 B = full 32-bank span (enables swizzle)

typedef __bf16 bf16x8 __attribute__((ext_vector_type(8)));
typedef float f32x4 __attribute__((ext_vector_type(4)));

static __device__ __forceinline__ float bf2f(unsigned short u) {
    union { unsigned int u; float f; } v; v.u = ((unsigned int)u) << 16; return v.f;
}
static __device__ __forceinline__ float2 bf2x(unsigned int u) {
    union { unsigned int x; float f; } lo, hi;
    lo.x = u << 16; hi.x = u & 0xffff0000u;
    float2 r; r.x = lo.f; r.y = hi.f; return r;
}
static __device__ __forceinline__ unsigned short f2bf(float f) {
    union { float f; unsigned int u; } v; v.f = f;
    unsigned int u = v.u;
    unsigned int r = (u + 0x7FFFu + ((u >> 16) & 1u)) >> 16;   // RNE
    return (unsigned short)r;
}

#define GLOAD_LDS16(g, l)                                                            \
    __builtin_amdgcn_global_load_lds((const __attribute__((address_space(1))) void*)(g), \
                                     (__attribute__((address_space(3))) void*)(l), 16, 0, 0)

// ---- fused prep: convM | convW | ed prep | W2->bf16 ----
#define NB_CONVM 3072              // (4096*768/4)/256
#define NB_CONVW 576               // 24*24
#define NB_PREP  900               // 300*768/256
#define NB_W2    3                 // 768/256

__global__ __launch_bounds__(256) void k_prep_all(
        const float* __restrict__ M, unsigned short* __restrict__ Mb,
        const float* __restrict__ W1, unsigned short* __restrict__ Wt,
        const float* __restrict__ ed_table, const float* __restrict__ b1,
        unsigned short* __restrict__ Epp,
        const float* __restrict__ W2, unsigned short* __restrict__ W2b) {
    const int blk = blockIdx.x;
    const int t = threadIdx.x;
    if (blk < NB_CONVM) {
        int idx = (blk * 256 + t) * 4;
        int row = idx / HIDDEN;
        ushort4 o;
        if (row < M_ROWS) {
            const float4 v = *(const float4*)(M + idx);
            o.x = f2bf(v.x); o.y = f2bf(v.y); o.z = f2bf(v.z); o.w = f2bf(v.w);
        } else {
            o.x = 0; o.y = 0; o.z = 0; o.w = 0;
        }
        *(ushort4*)(Mb + idx) = o;
    } else if (blk < NB_CONVM + NB_CONVW) {
        __shared__ float tile[32][68];
        int id = blk - NB_CONVM;
        int nt = id % 24, kt = id / 24;
        int n0 = nt * 64, k0 = kt * 32;
        int tk = t >> 4, tn = (t & 15) * 4;
        int srcRowOff = (n0 < HIDDEN) ? 0 : HIDDEN;
        int srcColBase = (n0 < HIDDEN) ? n0 : (n0 - HIDDEN);
        {
            const float4 v0 = *(const float4*)(W1 + (size_t)(k0 + tk + srcRowOff) * HIDDEN + srcColBase + tn);
            tile[tk][tn] = v0.x; tile[tk][tn + 1] = v0.y; tile[tk][tn + 2] = v0.z; tile[tk][tn + 3] = v0.w;
            const float4 v1 = *(const float4*)(W1 + (size_t)(k0 + tk + 16 + srcRowOff) * HIDDEN + srcColBase + tn);
            tile[tk + 16][tn] = v1.x; tile[tk + 16][tn + 1] = v1.y; tile[tk + 16][tn + 2] = v1.z; tile[tk + 16][tn + 3] = v1.w;
        }
        __syncthreads();
        int wn = t >> 2, wk = (t & 3) * 8;
        unsigned int p0 = (unsigned int)f2bf(tile[wk + 0][wn]) | ((unsigned int)f2bf(tile[wk + 1][wn]) << 16);
        unsigned int p1 = (unsigned int)f2bf(tile[wk + 2][wn]) | ((unsigned int)f2bf(tile[wk + 3][wn]) << 16);
        unsigned int p2 = (unsigned int)f2bf(tile[wk + 4][wn]) | ((unsigned int)f2bf(tile[wk + 5][wn]) << 16);
        unsigned int p3 = (unsigned int)f2bf(tile[wk + 6][wn]) | ((unsigned int)f2bf(tile[wk + 7][wn]) << 16);
        uint4 pk; pk.x = p0; pk.y = p1; pk.z = p2; pk.w = p3;
        *(uint4*)(Wt + (size_t)(n0 + wn) * HIDDEN + k0 + wk) = pk;
    } else if (blk < NB_CONVM + NB_CONVW + NB_PREP) {
        int id = (blk - NB_CONVM - NB_CONVW) * 256 + t;
        int e = id / HIDDEN, n = id - e * HIDDEN;
        float acc = b1[n];
#pragma unroll
        for (int k = 0; k < META; k++)
            acc += ed_table[e * META + k] * W1[(size_t)(2 * HIDDEN + k) * HIDDEN + n];
        Epp[id] = f2bf(acc);
    } else {
        int id = (blk - NB_CONVM - NB_CONVW - NB_PREP) * 256 + t;
        if (id < HIDDEN) W2b[id] = f2bf(W2[id]);
    }
}

// ---- AW[4096][1536] = Mb @ Wt^T ----
// 128x64 block tile, BK=64, grid 32x24 = 768 blocks = 3/CU. Swizzled LDS
// (k-line of row m rotated by (m%8)*8 shorts via global-side address) ->
// conflict-free ds_read_b128. (R7 verified: -5 us)
__global__ __launch_bounds__(256) void k_gemm(const unsigned short* __restrict__ Mb,
                                              const unsigned short* __restrict__ Wt,
                                              unsigned short* __restrict__ AW) {
    __shared__ unsigned short As[128 * BK];   // 16 KB
    __shared__ unsigned short Bs[64 * BK];    // 8 KB
    const int m0 = blockIdx.x * 128;
    const int n0 = blockIdx.y * 64;
    const int t = threadIdx.x, w = t >> 6, lane = t & 63;
    const int wm = (w & 1) * 64, wn = (w >> 1) * 32;
    const int q = lane >> 4, r = lane & 15;
    const int lrow = lane >> 3;
    const int lcol = ((((lane & 7) - lrow) & 7)) * 8;      // shorts
    const unsigned short* gA = Mb + (size_t)(m0 + w * 32 + lrow) * HIDDEN + lcol;
    const unsigned short* gB = Wt + (size_t)(n0 + w * 16 + lrow) * HIDDEN + lcol;
    unsigned short* lA = As + (w * 32) * BK;               // wave-uniform LDS base
    unsigned short* lB = Bs + (w * 16) * BK;
    f32x4 acc[4][2] = {};
    for (int k0 = 0; k0 < HIDDEN; k0 += BK) {
        GLOAD_LDS16(gA + k0, lA);
        GLOAD_LDS16(gA + k0 + 8 * HIDDEN,  lA + 8 * BK);
        GLOAD_LDS16(gA + k0 + 16 * HIDDEN, lA + 16 * BK);
        GLOAD_LDS16(gA + k0 + 24 * HIDDEN, lA + 24 * BK);
        GLOAD_LDS16(gB + k0, lB);
        GLOAD_LDS16(gB + k0 + 8 * HIDDEN,  lB + 8 * BK);
        __syncthreads();
        bf16x8 af[4][2], bfr[2][2];
        const int rs = r & 7;
#pragma unroll
        for (int i = 0; i < 4; i++)
#pragma unroll
            for (int s = 0; s < 2; s++)
                af[i][s] = *(const bf16x8*)&As[(wm + i * 16 + r) * BK + 8 * ((q + 4 * s + rs) & 7)];
#pragma unroll
        for (int j = 0; j < 2; j++)
#pragma unroll
            for (int s = 0; s < 2; s++)
                bfr[j][s] = *(const bf16x8*)&Bs[(wn + j * 16 + r) * BK + 8 * ((q + 4 * s + rs) & 7)];
#pragma unroll
        for (int i = 0; i < 4; i++)
#pragma unroll
            for (int j = 0; j < 2; j++) {
                acc[i][j] = __builtin_amdgcn_mfma_f32_16x16x32_bf16(af[i][0], bfr[j][0], acc[i][j], 0, 0, 0);
                acc[i][j] = __builtin_amdgcn_mfma_f32_16x16x32_bf16(af[i][1], bfr[j][1], acc[i][j], 0, 0, 0);
            }
        __syncthreads();
    }
    const int colb = n0 + wn + (lane & 15);
    const int rowb = m0 + wm + (lane >> 4) * 4;
#pragma unroll
    for (int i = 0; i < 4; i++)
#pragma unroll
        for (int j = 0; j < 2; j++) {
            unsigned short* dst = AW + (size_t)(rowb + i * 16) * N_OUT + colb + j * 16;
#pragma unroll
            for (int reg = 0; reg < 4; reg++)
                dst[(size_t)reg * N_OUT] = f2bf(acc[i][j][reg]);
        }
}

// ---- pair phase: 4 pairs per wave, ALL loads 16 B ----
// chunk0 [0,512): 64 lanes x 8 elems, 3 uint4/pair.
// chunk1 [512,768): lane-split per pair-duo — lanes 0-31 cover pair A's tail
// (32 x 8 elems), lanes 32-63 pair B's. 18 row loads/4 pairs (was 24, with 12
// half-width). Tail sums reduced with half-wave butterfly + shfl broadcast.
__global__ __launch_bounds__(256) void k_pair(const unsigned short* __restrict__ AW,
                                              const unsigned short* __restrict__ Epp,
                                              const unsigned short* __restrict__ W2b,
                                              const float* __restrict__ b2,
                                              const int* __restrict__ pairs,
                                              const int* __restrict__ eds,
                                              float* __restrict__ out) {
    const int wid = blockIdx.x * 4 + (threadIdx.x >> 6);   // 0..19999
    const int lane = threadIdx.x & 63;
    const int p0 = wid * 4;
    const int b = (p0 >= NPAIRS) ? 1 : 0;                   // 40000 % 4 == 0: group shares batch
    const int n0 = lane * 8;
    const int n1 = 512 + (lane & 31) * 8;
    const bool lo = lane < 32;

    const int4 pr01 = *(const int4*)(pairs + (size_t)p0 * 2);
    const int4 pr23 = *(const int4*)(pairs + (size_t)p0 * 2 + 4);
    const int4 ed4  = *(const int4*)(eds + p0);

    const size_t base = (size_t)(b * NMENT);
    const unsigned short* a1p0 = AW + (base + pr01.x) * N_OUT;
    const unsigned short* a2p0 = AW + (base + pr01.y) * N_OUT + HIDDEN;
    const unsigned short* ep0  = Epp + (size_t)ed4.x * HIDDEN;
    const unsigned short* a1p1 = AW + (base + pr01.z) * N_OUT;
    const unsigned short* a2p1 = AW + (base + pr01.w) * N_OUT + HIDDEN;
    const unsigned short* ep1  = Epp + (size_t)ed4.y * HIDDEN;
    const unsigned short* a1p2 = AW + (base + pr23.x) * N_OUT;
    const unsigned short* a2p2 = AW + (base + pr23.y) * N_OUT + HIDDEN;
    const unsigned short* ep2  = Epp + (size_t)ed4.z * HIDDEN;
    const unsigned short* a1p3 = AW + (base + pr23.z) * N_OUT;
    const unsigned short* a2p3 = AW + (base + pr23.w) * N_OUT + HIDDEN;
    const unsigned short* ep3  = Epp + (size_t)ed4.w * HIDDEN;

    // chunk1 lane-split pointers
    const unsigned short* c01a = lo ? a1p0 : a1p1;
    const unsigned short* c01b = lo ? a2p0 : a2p1;
    const unsigned short* c01e = lo ? ep0  : ep1;
    const unsigned short* c23a = lo ? a1p2 : a1p3;
    const unsigned short* c23b = lo ? a2p2 : a2p3;
    const unsigned short* c23e = lo ? ep2  : ep3;

    // all loads 16 B, all issued before any dependent use
    uint4 w0 = *(const uint4*)(W2b + n0);
    uint4 wc = *(const uint4*)(W2b + n1);
    uint4 x1 = *(const uint4*)(a1p0 + n0), x2 = *(const uint4*)(a2p0 + n0), xe = *(const uint4*)(ep0 + n0);
    uint4 y1 = *(const uint4*)(a1p1 + n0), y2 = *(const uint4*)(a2p1 + n0), ye = *(const uint4*)(ep1 + n0);
    uint4 z1 = *(const uint4*)(a1p2 + n0), z2 = *(const uint4*)(a2p2 + n0), ze = *(const uint4*)(ep2 + n0);
    uint4 v1 = *(const uint4*)(a1p3 + n0), v2 = *(const uint4*)(a2p3 + n0), ve = *(const uint4*)(ep3 + n0);
    uint4 q1 = *(const uint4*)(c01a + n1), q2 = *(const uint4*)(c01b + n1), qe = *(const uint4*)(c01e + n1);
    uint4 s1 = *(const uint4*)(c23a + n1), s2 = *(const uint4*)(c23b + n1), se = *(const uint4*)(c23e + n1);

    float acc0 = 0.f, acc1 = 0.f, acc2 = 0.f, acc3 = 0.f;
    float cacc01 = 0.f, cacc23 = 0.f;
#define ACC2(acc, ua, ub, ue, uw)                                              \
    {                                                                          \
        float2 fa = bf2x(ua), fb = bf2x(ub), fe = bf2x(ue), fw = bf2x(uw);     \
        float h0 = fmaxf(fa.x + fb.x + fe.x, 0.f);                             \
        float h1 = fmaxf(fa.y + fb.y + fe.y, 0.f);                             \
        acc += h0 * fw.x + h1 * fw.y;                                          \
    }
    ACC2(acc0, x1.x, x2.x, xe.x, w0.x); ACC2(acc0, x1.y, x2.y, xe.y, w0.y);
    ACC2(acc0, x1.z, x2.z, xe.z, w0.z); ACC2(acc0, x1.w, x2.w, xe.w, w0.w);
    ACC2(acc1, y1.x, y2.x, ye.x, w0.x); ACC2(acc1, y1.y, y2.y, ye.y, w0.y);
    ACC2(acc1, y1.z, y2.z, ye.z, w0.z); ACC2(acc1, y1.w, y2.w, ye.w, w0.w);
    ACC2(acc2, z1.x, z2.x, ze.x, w0.x); ACC2(acc2, z1.y, z2.y, ze.y, w0.y);
    ACC2(acc2, z1.z, z2.z, ze.z, w0.z); ACC2(acc2, z1.w, z2.w, ze.w, w0.w);
    ACC2(acc3, v1.x, v2.x, ve.x, w0.x); ACC2(acc3, v1.y, v2.y, ve.y, w0.y);
    ACC2(acc3, v1.z, v2.z, ve.z, w0.z); ACC2(acc3, v1.w, v2.w, ve.w, w0.w);
    ACC2(cacc01, q1.x, q2.x, qe.x, wc.x); ACC2(cacc01, q1.y, q2.y, qe.y, wc.y);
    ACC2(cacc01, q1.z, q2.z, qe.z, wc.z); ACC2(cacc01, q1.w, q2.w, qe.w, wc.w);
    ACC2(cacc23, s1.x, s2.x, se.x, wc.x); ACC2(cacc23, s1.y, s2.y, se.y, wc.y);
    ACC2(cacc23, s1.z, s2.z, se.z, wc.z); ACC2(cacc23, s1.w, s2.w, se.w, wc.w);
#undef ACC2
    // full-wave reduce for chunk0 accs
#pragma unroll
    for (int o = 32; o > 0; o >>= 1) {
        acc0 += __shfl_xor(acc0, o, 64);
        acc1 += __shfl_xor(acc1, o, 64);
        acc2 += __shfl_xor(acc2, o, 64);
        acc3 += __shfl_xor(acc3, o, 64);
    }
    // half-wave reduce for tail accs (xor < 32 stays within each half)
#pragma unroll
    for (int o = 16; o > 0; o >>= 1) {
        cacc01 += __shfl_xor(cacc01, o, 64);
        cacc23 += __shfl_xor(cacc23, o, 64);
    }
    const float t0 = __shfl(cacc01, 0, 64);   // pair 0 tail
    const float t1 = __shfl(cacc01, 32, 64);  // pair 1 tail
    const float t2 = __shfl(cacc23, 0, 64);   // pair 2 tail
    const float t3 = __shfl(cacc23, 32, 64);  // pair 3 tail
    if (lane == 0) {
        float bias = b2[0];
        float4 o;
        o.x = acc0 + t0 + bias;
        o.y = acc1 + t1 + bias;
        o.z = acc2 + t2 + bias;
        o.w = acc3 + t3 + bias;
        *(float4*)(out + p0) = o;
    }
}

extern "C" void kernel_launch(void* const* d_in, const int* in_sizes, int n_in,
                              void* d_out, int out_size, void* d_ws, size_t ws_size,
                              hipStream_t stream) {
    const float* mention  = (const float*)d_in[0];
    const int*   pairs    = (const int*)d_in[1];
    const int*   eds      = (const int*)d_in[2];
    const float* ed_table = (const float*)d_in[3];
    const float* W1       = (const float*)d_in[4];
    const float* b1       = (const float*)d_in[5];
    const float* W2       = (const float*)d_in[6];
    const float* b2       = (const float*)d_in[7];
    float* out = (float*)d_out;

    char* ws = (char*)d_ws;
    unsigned short* Mb  = (unsigned short*)(ws);                       // 4096*768*2  = 6,291,456
    unsigned short* Wt  = (unsigned short*)(ws + 6291456);             // 1536*768*2  = 2,359,296
    unsigned short* AW  = (unsigned short*)(ws + 8650752);             // 4096*1536*2 = 12,582,912
    unsigned short* Epp = (unsigned short*)(ws + 21233664);            // 300*768*2   = 460,800
    unsigned short* W2b = (unsigned short*)(ws + 21694464);            // 768*2

    k_prep_all<<<dim3(NB_CONVM + NB_CONVW + NB_PREP + NB_W2), dim3(256), 0, stream>>>(
        mention, Mb, W1, Wt, ed_table, b1, Epp, W2, W2b);
    k_gemm<<<dim3(M_PAD / 128, N_OUT / 64), dim3(256), 0, stream>>>(Mb, Wt, AW);
    k_pair<<<dim3(TOTAL_PAIRS / 16), dim3(256), 0, stream>>>(AW, Epp, W2b, b2, pairs, eds, out);
}